// Round 8
// baseline (186.122 us; speedup 1.0000x reference)
//
#include <hip/hip_runtime.h>
#include <math.h>

// Problem dims
#define Bb 2
#define Tt 16
#define Hh 64
#define Ww 64
#define Cc 64
#define ST_ (Hh*Ww*Cc)    // 262144
#define SH_ (Ww*Cc)       // 4096
#define SB_ (Tt*Hh*Ww*Cc) // 4194304
#define XELEMS (Bb*Tt*Hh*Ww*Cc)  // 8388608

#define TWO_PI 6.2831853071795864769f

typedef __attribute__((ext_vector_type(8))) short bf16x8;
typedef __attribute__((ext_vector_type(4))) float f32x4;

// workspace u32-offsets
#define OFF_PRE  8388608u
#define OFF_TWF  8390656u   // fwd W (real, K=64, re+im)    4096 u32
#define OFF_THF  8394752u   // fwd H (cpx K=128, re+im)     8192 u32
#define OFF_THI  8402944u   // inv H (cpx K=128, re+im, /64) 8192 u32
#define OFF_TWI  8411136u   // inv W (cpx K=128, re only, /64) 4096 u32

__device__ __forceinline__ float2 cmul(float2 a, float2 b) {
    return make_float2(fmaf(a.x, b.x, -a.y * b.y), fmaf(a.x, b.y, a.y * b.x));
}
__device__ __forceinline__ float2 cadd(float2 a, float2 b) { return make_float2(a.x + b.x, a.y + b.y); }
__device__ __forceinline__ float2 csub(float2 a, float2 b) { return make_float2(a.x - b.x, a.y - b.y); }

// bf16 pair pack/unpack (x -> low 16, y -> high 16). RNE; range = fp32.
__device__ __forceinline__ unsigned bfpack(float2 f) {
    unsigned r = __float_as_uint(f.x);
    unsigned i = __float_as_uint(f.y);
    r = (r + 0x7fffu + ((r >> 16) & 1u)) >> 16;
    i = (i + 0x7fffu + ((i >> 16) & 1u)) >> 16;
    return r | (i << 16);
}
__device__ __forceinline__ float2 bfunpack(unsigned u) {
    return make_float2(__uint_as_float(u << 16), __uint_as_float(u & 0xffff0000u));
}

template <int S>
__device__ __forceinline__ void fft4(float2& a, float2& b, float2& c, float2& d) {
    float2 t0 = cadd(a, c), t1 = csub(a, c);
    float2 t2 = cadd(b, d), t3 = csub(b, d);
    a = cadd(t0, t2);
    c = csub(t0, t2);
    b = make_float2(t1.x - (float)S * t3.y, t1.y + (float)S * t3.x);
    d = make_float2(t1.x + (float)S * t3.y, t1.y - (float)S * t3.x);
}

// 16-pt FFT in registers, natural order in/out, radix 4x4.
template <int S>
__device__ __forceinline__ void fft16(float2 v[16]) {
    const float CS[10] = {1.f, 0.92387953f, 0.70710678f, 0.38268343f, 0.f,
                          -0.38268343f, -0.70710678f, -0.92387953f, -1.f, -0.92387953f};
    const float SN[10] = {0.f, 0.38268343f, 0.70710678f, 0.92387953f, 1.f,
                          0.92387953f, 0.70710678f, 0.38268343f, 0.f, -0.38268343f};
    float2 A[4][4];
#pragma unroll
    for (int j = 0; j < 4; ++j) {
        A[j][0] = v[j]; A[j][1] = v[4 + j]; A[j][2] = v[8 + j]; A[j][3] = v[12 + j];
        fft4<S>(A[j][0], A[j][1], A[j][2], A[j][3]);
#pragma unroll
        for (int k0 = 0; k0 < 4; ++k0) {
            int m = j * k0;
            float2 tw = make_float2(CS[m], (float)S * SN[m]);
            A[j][k0] = cmul(A[j][k0], tw);
        }
    }
#pragma unroll
    for (int k0 = 0; k0 < 4; ++k0) {
        fft4<S>(A[0][k0], A[1][k0], A[2][k0], A[3][k0]);
        v[k0] = A[0][k0]; v[k0 + 4] = A[1][k0]; v[k0 + 8] = A[2][k0]; v[k0 + 12] = A[3][k0];
    }
}

// ---------------------------------------------------------------------------
// Setup: build delta-W MFMA fragments + 4 twiddle A-fragment tables.
// Table layout (u32): T[(((reim*4 + r)*KA_N + ka)*64 + lane)*4 + p]
//   u32 = pack(A[wp][k0], A[wp][k0+1]), wp=16r+(lane&15), k0=ka*32+(lane>>4)*8+2p
// ---------------------------------------------------------------------------
__global__ __launch_bounds__(256) void k_setup(const float* __restrict__ dW,
                                               unsigned* __restrict__ ws) {
    int j = blockIdx.x * 256 + threadIdx.x;   // 0..26623
    if (j < 2048) {
        // pre: W B-fragments for k_mid
        int p2 = j & 3, lane = (j >> 2) & 63, ka = (j >> 8) & 1, nt = j >> 9;
        int kb = ka * 32 + (lane >> 4) * 8 + 2 * p2;
        int ccol = (lane & 15) + 16 * nt;
        ws[OFF_PRE + j] = bfpack(make_float2(dW[kb * 64 + ccol], dW[(kb + 1) * 64 + ccol]));
        return;
    }
    int idx, table;
    if (j < 6144)       { idx = j - 2048;  table = 0; }   // T_wf
    else if (j < 14336) { idx = j - 6144;  table = 1; }   // T_hf
    else if (j < 22528) { idx = j - 14336; table = 2; }   // T_hi
    else                { idx = j - 22528; table = 3; }   // T_wi
    int p = idx & 3;
    int lane = (idx >> 2) & 63;
    int m = lane & 15, q = lane >> 4;
    int ka, r, reim;
    if (table == 0)      { ka = (idx >> 8) & 1; r = (idx >> 9) & 3;  reim = (idx >> 11) & 1; }
    else if (table == 3) { ka = (idx >> 8) & 3; r = (idx >> 10) & 3; reim = 0; }
    else                 { ka = (idx >> 8) & 3; r = (idx >> 10) & 3; reim = (idx >> 12) & 1; }
    int wp = r * 16 + m;
    int k0 = ka * 32 + q * 8 + 2 * p;
    float val[2];
#pragma unroll
    for (int dk = 0; dk < 2; ++dk) {
        int k = k0 + dk;
        float v;
        if (table == 0) {
            // fwd W, real input, K=64 (k = w). S=-1: re=cos, im=-sin
            int a = (wp * k) & 63;
            float sn, cs; sincosf(TWO_PI * (float)a * (1.0f / 64.0f), &sn, &cs);
            v = (reim == 0) ? cs : -sn;
        } else {
            int h = k >> 1;
            int a = (wp * h) & 63;
            float sn, cs; sincosf(TWO_PI * (float)a * (1.0f / 64.0f), &sn, &cs);
            bool even = (k & 1) == 0;
            if (table == 1) {               // fwd H: S=-1, sc=1
                v = (reim == 0) ? (even ? cs : sn) : (even ? -sn : cs);
            } else if (table == 2) {        // inv H: S=+1, sc=1/64
                v = (reim == 0) ? (even ? cs : -sn) : (even ? sn : cs);
                v *= (1.0f / 64.0f);
            } else {                        // inv W (re only): S=+1, sc=1/64
                v = (even ? cs : -sn) * (1.0f / 64.0f);
            }
        }
        val[dk] = v;
    }
    unsigned base = (table == 0) ? OFF_TWF : (table == 1) ? OFF_THF
                  : (table == 2) ? OFF_THI : OFF_TWI;
    ws[base + idx] = bfpack(make_float2(val[0], val[1]));
}

// ---------------------------------------------------------------------------
// MFMA DFT-64 along W, real fp32 in -> packed bf16 complex out. wg per (b,t,h).
// ---------------------------------------------------------------------------
__global__ __launch_bounds__(256) void k_dft_w_fwd(const float* __restrict__ x,
                                                   unsigned* __restrict__ X,
                                                   const uint4* __restrict__ T) {
    __shared__ float xsl[64 * 65];
    int tid = threadIdx.x;
    int sbase = blockIdx.x * 4096;
    for (int i = tid; i < 4096; i += 256)
        xsl[(i >> 6) * 65 + (i & 63)] = x[sbase + i];
    __syncthreads();

    int r = tid >> 6, lane = tid & 63;
    int m = lane & 15, q = lane >> 4;
    union U48 { uint4 u4; unsigned u[4]; bf16x8 v8; };
    U48 Are[2], Aim[2], Bf;
#pragma unroll
    for (int ka = 0; ka < 2; ++ka) {
        Are[ka].u4 = T[((0 * 4 + r) * 2 + ka) * 64 + lane];
        Aim[ka].u4 = T[((1 * 4 + r) * 2 + ka) * 64 + lane];
    }
    f32x4 ar[4], ai[4];
#pragma unroll
    for (int nt = 0; nt < 4; ++nt) { ar[nt] = (f32x4){0.f,0.f,0.f,0.f}; ai[nt] = (f32x4){0.f,0.f,0.f,0.f}; }
#pragma unroll
    for (int nt = 0; nt < 4; ++nt) {
        int cc = m + 16 * nt;
#pragma unroll
        for (int ka = 0; ka < 2; ++ka) {
            int w0 = ka * 32 + q * 8;
#pragma unroll
            for (int p = 0; p < 4; ++p)
                Bf.u[p] = bfpack(make_float2(xsl[(w0 + 2 * p) * 65 + cc],
                                             xsl[(w0 + 2 * p + 1) * 65 + cc]));
            ar[nt] = __builtin_amdgcn_mfma_f32_16x16x32_bf16(Are[ka].v8, Bf.v8, ar[nt], 0, 0, 0);
            ai[nt] = __builtin_amdgcn_mfma_f32_16x16x32_bf16(Aim[ka].v8, Bf.v8, ai[nt], 0, 0, 0);
        }
    }
#pragma unroll
    for (int nt = 0; nt < 4; ++nt) {
        int cc = m + 16 * nt;
#pragma unroll
        for (int reg = 0; reg < 4; ++reg) {
            int wp = r * 16 + q * 4 + reg;
            X[sbase + wp * 64 + cc] = bfpack(make_float2(ar[nt][reg], ai[nt][reg]));
        }
    }
}

// ---------------------------------------------------------------------------
// MFMA DFT-64 along H, packed complex in-place (K=128 interleaved re/im).
// wg per (b,t,w). Direction + scale baked into table T.
// ---------------------------------------------------------------------------
__global__ __launch_bounds__(256) void k_dft_h(unsigned* __restrict__ X,
                                               const uint4* __restrict__ T) {
    __shared__ unsigned zs[64 * 68];
    int tid = threadIdx.x;
    int s = blockIdx.x;
    int bt = s >> 6, w = s & 63;
    int base = bt * ST_ + w * 64;
    for (int i = tid; i < 4096; i += 256)
        zs[(i >> 6) * 68 + (i & 63)] = X[base + (i >> 6) * SH_ + (i & 63)];
    __syncthreads();

    int r = tid >> 6, lane = tid & 63;
    int m = lane & 15, q = lane >> 4;
    union U48 { uint4 u4; unsigned u[4]; bf16x8 v8; };
    U48 Are[4], Aim[4], Bf;
#pragma unroll
    for (int ka = 0; ka < 4; ++ka) {
        Are[ka].u4 = T[((0 * 4 + r) * 4 + ka) * 64 + lane];
        Aim[ka].u4 = T[((1 * 4 + r) * 4 + ka) * 64 + lane];
    }
    f32x4 ar[4], ai[4];
#pragma unroll
    for (int nt = 0; nt < 4; ++nt) { ar[nt] = (f32x4){0.f,0.f,0.f,0.f}; ai[nt] = (f32x4){0.f,0.f,0.f,0.f}; }
#pragma unroll
    for (int nt = 0; nt < 4; ++nt) {
        int cc = m + 16 * nt;
#pragma unroll
        for (int ka = 0; ka < 4; ++ka) {
            int h0 = ka * 16 + q * 4;
            Bf.u[0] = zs[(h0 + 0) * 68 + cc];
            Bf.u[1] = zs[(h0 + 1) * 68 + cc];
            Bf.u[2] = zs[(h0 + 2) * 68 + cc];
            Bf.u[3] = zs[(h0 + 3) * 68 + cc];
            ar[nt] = __builtin_amdgcn_mfma_f32_16x16x32_bf16(Are[ka].v8, Bf.v8, ar[nt], 0, 0, 0);
            ai[nt] = __builtin_amdgcn_mfma_f32_16x16x32_bf16(Aim[ka].v8, Bf.v8, ai[nt], 0, 0, 0);
        }
    }
#pragma unroll
    for (int nt = 0; nt < 4; ++nt) {
        int cc = m + 16 * nt;
#pragma unroll
        for (int reg = 0; reg < 4; ++reg) {
            int hp = r * 16 + q * 4 + reg;
            X[base + hp * SH_ + cc] = bfpack(make_float2(ar[nt][reg], ai[nt][reg]));
        }
    }
}

// ---------------------------------------------------------------------------
// MFMA inverse DFT-64 along W, packed complex -> real fp32 out (re only).
// wg per (b,t,h). Scale 1/64 in table.
// ---------------------------------------------------------------------------
__global__ __launch_bounds__(256) void k_dft_w_inv(const unsigned* __restrict__ X,
                                                   float* __restrict__ out,
                                                   const uint4* __restrict__ T) {
    __shared__ unsigned zs[64 * 68];
    int tid = threadIdx.x;
    int sbase = blockIdx.x * 4096;
    for (int i = tid; i < 4096; i += 256)
        zs[(i >> 6) * 68 + (i & 63)] = X[sbase + i];
    __syncthreads();

    int r = tid >> 6, lane = tid & 63;
    int m = lane & 15, q = lane >> 4;
    union U48 { uint4 u4; unsigned u[4]; bf16x8 v8; };
    U48 Are[4], Bf;
#pragma unroll
    for (int ka = 0; ka < 4; ++ka)
        Are[ka].u4 = T[(r * 4 + ka) * 64 + lane];
    f32x4 ar[4];
#pragma unroll
    for (int nt = 0; nt < 4; ++nt) ar[nt] = (f32x4){0.f,0.f,0.f,0.f};
#pragma unroll
    for (int nt = 0; nt < 4; ++nt) {
        int cc = m + 16 * nt;
#pragma unroll
        for (int ka = 0; ka < 4; ++ka) {
            int w0 = ka * 16 + q * 4;
            Bf.u[0] = zs[(w0 + 0) * 68 + cc];
            Bf.u[1] = zs[(w0 + 1) * 68 + cc];
            Bf.u[2] = zs[(w0 + 2) * 68 + cc];
            Bf.u[3] = zs[(w0 + 3) * 68 + cc];
            ar[nt] = __builtin_amdgcn_mfma_f32_16x16x32_bf16(Are[ka].v8, Bf.v8, ar[nt], 0, 0, 0);
        }
    }
#pragma unroll
    for (int nt = 0; nt < 4; ++nt) {
        int cc = m + 16 * nt;
#pragma unroll
        for (int reg = 0; reg < 4; ++reg) {
            int wp = r * 16 + q * 4 + reg;
            out[sbase + wp * 64 + cc] = ar[nt][reg];
        }
    }
}

// ---------------------------------------------------------------------------
// Fused: FFT-16 fwd along T + gates + MFMA delta-matmul + scan + FFT-16 inv.
// 256 thr = 4 waves = 4 sites (b,h,w); lane = channel c. Output scaled 1/16.
// ---------------------------------------------------------------------------
__global__ __launch_bounds__(256) void k_mid(
    const float* __restrict__ x, unsigned* __restrict__ X,
    const float* __restrict__ Ak, const float* __restrict__ Bk,
    const float* __restrict__ fb, const float* __restrict__ fs,
    const float* __restrict__ ib, const float* __restrict__ isc_,
    const uint4* __restrict__ pre, const float* __restrict__ db) {
    const float CT[16] = {1.f, 0.9238795f, 0.7071068f, 0.3826834f, 0.f, -0.3826834f,
                          -0.7071068f, -0.9238795f, -1.f, -0.9238795f, -0.7071068f,
                          -0.3826834f, 0.f, 0.3826834f, 0.7071068f, 0.9238795f};
    const float SN[16] = {0.f, 0.3826834f, 0.7071068f, 0.9238795f, 1.f, 0.9238795f,
                          0.7071068f, 0.3826834f, 0.f, -0.3826834f, -0.7071068f,
                          -0.9238795f, -1.f, -0.9238795f, -0.7071068f, -0.3826834f};
    __shared__ float Akl[1728], Bkl[1728];
    __shared__ __align__(16) float xs[4][16 * 68 + 4];

    int tid = threadIdx.x;
    int g = tid >> 6, lane = tid & 63;
    int c = lane;
    int site = blockIdx.x * 4 + g;
    int b = site >> 12, hw = site & 4095;
    int h = hw >> 6, w = hw & 63;
    int base = b * SB_ + hw * 64;

    for (int i = tid; i < 1728; i += 256) { Akl[i] = Ak[i]; Bkl[i] = Bk[i]; }

    float xv[16];
    float2 v[16];
#pragma unroll
    for (int t = 0; t < 16; ++t) {
        xv[t] = x[base + t * ST_ + c];
        v[t] = bfunpack(X[base + t * ST_ + c]);
    }
#pragma unroll
    for (int t = 0; t < 16; ++t) xs[g][t * 68 + c] = xv[t];
    __syncthreads();

    // MFMA delta matmul: D[t][ccol] = sum_d x[t][d] W[d][ccol] + db
    int m = lane & 15, q = lane >> 4;
    bf16x8 Afrag[2];
#pragma unroll
    for (int ka = 0; ka < 2; ++ka) {
        int d0 = ka * 32 + q * 8;
        const float* p = &xs[g][m * 68 + d0];
        float4 f0 = *(const float4*)p;
        float4 f1 = *(const float4*)(p + 4);
        union { bf16x8 v8; unsigned u[4]; } U;
        U.u[0] = bfpack(make_float2(f0.x, f0.y));
        U.u[1] = bfpack(make_float2(f0.z, f0.w));
        U.u[2] = bfpack(make_float2(f1.x, f1.y));
        U.u[3] = bfpack(make_float2(f1.z, f1.w));
        Afrag[ka] = U.v8;
    }
#pragma unroll
    for (int nt = 0; nt < 4; ++nt) {
        int ccol = m + 16 * nt;
        float dbn = db[ccol];
        f32x4 acc = {dbn, dbn, dbn, dbn};
#pragma unroll
        for (int ka = 0; ka < 2; ++ka) {
            union { bf16x8 v8; uint4 u4; } Ub;
            Ub.u4 = pre[(nt * 2 + ka) * 64 + lane];
            acc = __builtin_amdgcn_mfma_f32_16x16x32_bf16(Afrag[ka], Ub.v8, acc, 0, 0, 0);
        }
#pragma unroll
        for (int reg = 0; reg < 4; ++reg)
            xs[g][(q * 4 + reg) * 68 + ccol] = acc[reg];
    }

    // A_f/B_f generators from the 27 taps
    float sh, ch; sincosf(TWO_PI * (float)h / 64.0f, &sh, &ch);
    float sw, cw; sincosf(TWO_PI * (float)w / 64.0f, &sw, &cw);
    float2 eh[3] = { make_float2(ch, sh), make_float2(1.f, 0.f), make_float2(ch, -sh) };
    float2 ew[3] = { make_float2(cw, sw), make_float2(1.f, 0.f), make_float2(cw, -sw) };
    float2 GA[3], GB[3];
#pragma unroll
    for (int kt = 0; kt < 3; ++kt) { GA[kt] = make_float2(0.f, 0.f); GB[kt] = make_float2(0.f, 0.f); }
#pragma unroll
    for (int kh = 0; kh < 3; ++kh) {
#pragma unroll
        for (int kw = 0; kw < 3; ++kw) {
            float2 e = cmul(eh[kh], ew[kw]);
#pragma unroll
            for (int kt = 0; kt < 3; ++kt) {
                float ka = Akl[c * 27 + kt * 9 + kh * 3 + kw];
                float kb = Bkl[c * 27 + kt * 9 + kh * 3 + kw];
                GA[kt].x = fmaf(ka, e.x, GA[kt].x);
                GA[kt].y = fmaf(ka, e.y, GA[kt].y);
                GB[kt].x = fmaf(kb, e.x, GB[kt].x);
                GB[kt].y = fmaf(kb, e.y, GB[kt].y);
            }
        }
    }
    float fbc = fb[c], fsc = fs[c], ibc = ib[c], iscv = isc_[c];

    fft16<-1>(v);
    __syncthreads();

    float delta_raw[16];
#pragma unroll
    for (int t = 0; t < 16; ++t) delta_raw[t] = xs[g][t * 68 + c];

    float2 hv = make_float2(0.f, 0.f);
#pragma unroll
    for (int t = 0; t < 16; ++t) {
        float ct = CT[t], st = SN[t];
        float2 Af, Bf;
        Af.x = GA[1].x + ct * (GA[0].x + GA[2].x) - st * (GA[0].y - GA[2].y);
        Af.y = GA[1].y + ct * (GA[0].y + GA[2].y) + st * (GA[0].x - GA[2].x);
        Bf.x = GB[1].x + ct * (GB[0].x + GB[2].x) - st * (GB[0].y - GB[2].y);
        Bf.y = GB[1].y + ct * (GB[0].y + GB[2].y) + st * (GB[0].x - GB[2].x);

        float xc = xv[t];
        float fg  = __builtin_amdgcn_rcpf(1.f + __expf(-(fbc + fsc * xc)));
        float igv = __builtin_amdgcn_rcpf(1.f + __expf(-(ibc + iscv * xc)));
        float dot = delta_raw[t];
        float delta = (dot > 20.f) ? dot : __logf(1.f + __expf(dot));

        float sR = igv * delta;
        float2 bbv;
        bbv.x = sR * (Bf.x * v[t].x - Bf.y * v[t].y);
        bbv.y = sR * (Bf.x * v[t].y + Bf.y * v[t].x);
        float2 av = make_float2(fg * Af.x, fg * Af.y);
        float2 nh;
        nh.x = av.x * hv.x - av.y * hv.y + bbv.x;
        nh.y = av.x * hv.y + av.y * hv.x + bbv.y;
        hv = nh;
        v[t] = hv;
    }

    fft16<1>(v);

#pragma unroll
    for (int t = 0; t < 16; ++t) {
        float2 o = make_float2(v[t].x * 0.0625f, v[t].y * 0.0625f);
        X[base + t * ST_ + c] = bfpack(o);
    }
}

extern "C" void kernel_launch(void* const* d_in, const int* in_sizes, int n_in,
                              void* d_out, int out_size, void* d_ws, size_t ws_size,
                              hipStream_t stream) {
    const float* x   = (const float*)d_in[0];
    const float* Ak  = (const float*)d_in[1];
    const float* Bk  = (const float*)d_in[2];
    const float* fb  = (const float*)d_in[3];
    const float* fs  = (const float*)d_in[4];
    const float* ib  = (const float*)d_in[5];
    const float* is_ = (const float*)d_in[6];
    const float* dW  = (const float*)d_in[7];
    const float* db  = (const float*)d_in[8];
    float* out = (float*)d_out;
    unsigned* ws = (unsigned*)d_ws;
    unsigned* X = ws;  // packed bf16 complex, 33.5 MB

    k_setup<<<104, 256, 0, stream>>>(dW, ws);
    k_dft_w_fwd<<<Bb * Tt * Hh, 256, 0, stream>>>(x, X, (const uint4*)(ws + OFF_TWF));
    k_dft_h<<<Bb * Tt * Ww, 256, 0, stream>>>(X, (const uint4*)(ws + OFF_THF));
    k_mid<<<(Bb * Hh * Ww) / 4, 256, 0, stream>>>(x, X, Ak, Bk, fb, fs, ib, is_,
                                                  (const uint4*)(ws + OFF_PRE), db);
    k_dft_h<<<Bb * Tt * Ww, 256, 0, stream>>>(X, (const uint4*)(ws + OFF_THI));
    k_dft_w_inv<<<Bb * Tt * Hh, 256, 0, stream>>>(X, out, (const uint4*)(ws + OFF_TWI));
}

// Round 9
// 171.730 us; speedup vs baseline: 1.0838x; 1.0838x over previous
//
#include <hip/hip_runtime.h>
#include <math.h>

// Problem dims
#define Bb 2
#define Tt 16
#define Hh 64
#define Ww 64
#define Cc 64
#define ST_ (Hh*Ww*Cc)    // 262144
#define SB_ (Tt*Hh*Ww*Cc) // 4194304

#define TWO_PI 6.2831853071795864769f

typedef __attribute__((ext_vector_type(8))) short bf16x8;
typedef __attribute__((ext_vector_type(4))) float f32x4;

// workspace u32-offsets: two ping-pong X buffers + tables
#define BUF_A    0u
#define BUF_B    8388608u
#define OFF_PRE  16777216u
#define OFF_TWF  16779264u   // fwd W (real, K=64, re+im)      4096 u32
#define OFF_THF  16783360u   // fwd H (cpx K=128, re+im)       8192 u32
#define OFF_THI  16791552u   // inv H (cpx K=128, re+im, /64)  8192 u32
#define OFF_TWI  16799744u   // inv W (cpx K=128, re only,/64) 4096 u32

__device__ __forceinline__ float2 cmul(float2 a, float2 b) {
    return make_float2(fmaf(a.x, b.x, -a.y * b.y), fmaf(a.x, b.y, a.y * b.x));
}
__device__ __forceinline__ float2 cadd(float2 a, float2 b) { return make_float2(a.x + b.x, a.y + b.y); }
__device__ __forceinline__ float2 csub(float2 a, float2 b) { return make_float2(a.x - b.x, a.y - b.y); }

// bf16 pair pack/unpack (x -> low 16, y -> high 16). RNE; range = fp32.
__device__ __forceinline__ unsigned bfpack(float2 f) {
    unsigned r = __float_as_uint(f.x);
    unsigned i = __float_as_uint(f.y);
    r = (r + 0x7fffu + ((r >> 16) & 1u)) >> 16;
    i = (i + 0x7fffu + ((i >> 16) & 1u)) >> 16;
    return r | (i << 16);
}
__device__ __forceinline__ float2 bfunpack(unsigned u) {
    return make_float2(__uint_as_float(u << 16), __uint_as_float(u & 0xffff0000u));
}

template <int S>
__device__ __forceinline__ void fft4(float2& a, float2& b, float2& c, float2& d) {
    float2 t0 = cadd(a, c), t1 = csub(a, c);
    float2 t2 = cadd(b, d), t3 = csub(b, d);
    a = cadd(t0, t2);
    c = csub(t0, t2);
    b = make_float2(t1.x - (float)S * t3.y, t1.y + (float)S * t3.x);
    d = make_float2(t1.x + (float)S * t3.y, t1.y - (float)S * t3.x);
}

// 16-pt FFT in registers, natural order in/out, radix 4x4.
template <int S>
__device__ __forceinline__ void fft16(float2 v[16]) {
    const float CS[10] = {1.f, 0.92387953f, 0.70710678f, 0.38268343f, 0.f,
                          -0.38268343f, -0.70710678f, -0.92387953f, -1.f, -0.92387953f};
    const float SN[10] = {0.f, 0.38268343f, 0.70710678f, 0.92387953f, 1.f,
                          0.92387953f, 0.70710678f, 0.38268343f, 0.f, -0.38268343f};
    float2 A[4][4];
#pragma unroll
    for (int j = 0; j < 4; ++j) {
        A[j][0] = v[j]; A[j][1] = v[4 + j]; A[j][2] = v[8 + j]; A[j][3] = v[12 + j];
        fft4<S>(A[j][0], A[j][1], A[j][2], A[j][3]);
#pragma unroll
        for (int k0 = 0; k0 < 4; ++k0) {
            int m = j * k0;
            float2 tw = make_float2(CS[m], (float)S * SN[m]);
            A[j][k0] = cmul(A[j][k0], tw);
        }
    }
#pragma unroll
    for (int k0 = 0; k0 < 4; ++k0) {
        fft4<S>(A[0][k0], A[1][k0], A[2][k0], A[3][k0]);
        v[k0] = A[0][k0]; v[k0 + 4] = A[1][k0]; v[k0 + 8] = A[2][k0]; v[k0 + 12] = A[3][k0];
    }
}

// ---------------------------------------------------------------------------
// Setup: delta-W MFMA fragments + 4 twiddle A-fragment tables (unchanged math).
// ---------------------------------------------------------------------------
__global__ __launch_bounds__(256) void k_setup(const float* __restrict__ dW,
                                               unsigned* __restrict__ ws) {
    int j = blockIdx.x * 256 + threadIdx.x;   // 0..26623
    if (j < 2048) {
        int p2 = j & 3, lane = (j >> 2) & 63, ka = (j >> 8) & 1, nt = j >> 9;
        int kb = ka * 32 + (lane >> 4) * 8 + 2 * p2;
        int ccol = (lane & 15) + 16 * nt;
        ws[OFF_PRE + j] = bfpack(make_float2(dW[kb * 64 + ccol], dW[(kb + 1) * 64 + ccol]));
        return;
    }
    int idx, table;
    if (j < 6144)       { idx = j - 2048;  table = 0; }   // T_wf
    else if (j < 14336) { idx = j - 6144;  table = 1; }   // T_hf
    else if (j < 22528) { idx = j - 14336; table = 2; }   // T_hi
    else                { idx = j - 22528; table = 3; }   // T_wi
    int p = idx & 3;
    int lane = (idx >> 2) & 63;
    int m = lane & 15, q = lane >> 4;
    int ka, r, reim;
    if (table == 0)      { ka = (idx >> 8) & 1; r = (idx >> 9) & 3;  reim = (idx >> 11) & 1; }
    else if (table == 3) { ka = (idx >> 8) & 3; r = (idx >> 10) & 3; reim = 0; }
    else                 { ka = (idx >> 8) & 3; r = (idx >> 10) & 3; reim = (idx >> 12) & 1; }
    int wp = r * 16 + m;
    int k0 = ka * 32 + q * 8 + 2 * p;
    float val[2];
#pragma unroll
    for (int dk = 0; dk < 2; ++dk) {
        int k = k0 + dk;
        float v;
        if (table == 0) {
            int a = (wp * k) & 63;
            float sn, cs; sincosf(TWO_PI * (float)a * (1.0f / 64.0f), &sn, &cs);
            v = (reim == 0) ? cs : -sn;
        } else {
            int h = k >> 1;
            int a = (wp * h) & 63;
            float sn, cs; sincosf(TWO_PI * (float)a * (1.0f / 64.0f), &sn, &cs);
            bool even = (k & 1) == 0;
            if (table == 1) {
                v = (reim == 0) ? (even ? cs : sn) : (even ? -sn : cs);
            } else if (table == 2) {
                v = (reim == 0) ? (even ? cs : -sn) : (even ? sn : cs);
                v *= (1.0f / 64.0f);
            } else {
                v = (even ? cs : -sn) * (1.0f / 64.0f);
            }
        }
        val[dk] = v;
    }
    unsigned base = (table == 0) ? OFF_TWF : (table == 1) ? OFF_THF
                  : (table == 2) ? OFF_THI : OFF_TWI;
    ws[base + idx] = bfpack(make_float2(val[0], val[1]));
}

// ---------------------------------------------------------------------------
// Pass 1: MFMA DFT-64 along W. x (b,t,h,w,c) fp32 contiguous slab ->
// X1 (b,t,w,h,c) packed bf16 complex. wg per (b,t,h). LDS staged c-major
// as bf16 pairs (stride 66, ds_read_b64 fragments).
// ---------------------------------------------------------------------------
__global__ __launch_bounds__(256) void k_dft_w_fwd(const float* __restrict__ x,
                                                   unsigned* __restrict__ X1,
                                                   const uint4* __restrict__ T) {
    __shared__ unsigned zw[64 * 66];   // [c][i], i = w/2 pair index (i<32)
    int tid = threadIdx.x;
    int s = blockIdx.x;                // (b,t,h)
    const float* src = x + (size_t)s * 4096;
    for (int idx = tid; idx < 2048; idx += 256) {
        int i = idx >> 6, c = idx & 63;
        zw[c * 66 + i] = bfpack(make_float2(src[i * 128 + c], src[i * 128 + 64 + c]));
    }
    __syncthreads();

    int r = tid >> 6, lane = tid & 63;
    int m = lane & 15, q = lane >> 4;
    union U48 { uint4 u4; uint2 u2[2]; unsigned u[4]; bf16x8 v8; };
    U48 Are[2], Aim[2], Bf;
#pragma unroll
    for (int ka = 0; ka < 2; ++ka) {
        Are[ka].u4 = T[((0 * 4 + r) * 2 + ka) * 64 + lane];
        Aim[ka].u4 = T[((1 * 4 + r) * 2 + ka) * 64 + lane];
    }
    f32x4 ar[4], ai[4];
#pragma unroll
    for (int nt = 0; nt < 4; ++nt) { ar[nt] = (f32x4){0.f,0.f,0.f,0.f}; ai[nt] = (f32x4){0.f,0.f,0.f,0.f}; }
#pragma unroll
    for (int nt = 0; nt < 4; ++nt) {
        int cc = m + 16 * nt;
#pragma unroll
        for (int ka = 0; ka < 2; ++ka) {
            int i0 = ka * 16 + q * 4;
            Bf.u2[0] = *(const uint2*)&zw[cc * 66 + i0];
            Bf.u2[1] = *(const uint2*)&zw[cc * 66 + i0 + 2];
            ar[nt] = __builtin_amdgcn_mfma_f32_16x16x32_bf16(Are[ka].v8, Bf.v8, ar[nt], 0, 0, 0);
            ai[nt] = __builtin_amdgcn_mfma_f32_16x16x32_bf16(Aim[ka].v8, Bf.v8, ai[nt], 0, 0, 0);
        }
    }
    // write X1 (b,t,w',h,c): bt = s>>6, h = s&63
    int bt = s >> 6, h = s & 63;
    size_t ob = (size_t)bt * 262144 + (size_t)h * 64;
#pragma unroll
    for (int nt = 0; nt < 4; ++nt) {
        int cc = m + 16 * nt;
#pragma unroll
        for (int reg = 0; reg < 4; ++reg) {
            int wp = r * 16 + q * 4 + reg;
            X1[ob + (size_t)wp * 4096 + cc] = bfpack(make_float2(ar[nt][reg], ai[nt][reg]));
        }
    }
}

// ---------------------------------------------------------------------------
// Pass 2: MFMA DFT-64 along H (K=128 interleaved re/im). X1 (b,t,w,h,c)
// contiguous slab -> X2 (b,h,w,t,c). wg per (b,t,w).
// ---------------------------------------------------------------------------
__global__ __launch_bounds__(256) void k_dft_h_fwd(const unsigned* __restrict__ X1,
                                                   unsigned* __restrict__ X2,
                                                   const uint4* __restrict__ T) {
    __shared__ unsigned zs[64 * 66];   // [c][h]
    int tid = threadIdx.x;
    int s = blockIdx.x;                // (b,t,w)
    const unsigned* src = X1 + (size_t)s * 4096;
    for (int i = tid; i < 4096; i += 256) {
        int h = i >> 6, c = i & 63;
        zs[c * 66 + h] = src[i];
    }
    __syncthreads();

    int r = tid >> 6, lane = tid & 63;
    int m = lane & 15, q = lane >> 4;
    union U48 { uint4 u4; uint2 u2[2]; unsigned u[4]; bf16x8 v8; };
    U48 Are[4], Aim[4], Bf;
#pragma unroll
    for (int ka = 0; ka < 4; ++ka) {
        Are[ka].u4 = T[((0 * 4 + r) * 4 + ka) * 64 + lane];
        Aim[ka].u4 = T[((1 * 4 + r) * 4 + ka) * 64 + lane];
    }
    f32x4 ar[4], ai[4];
#pragma unroll
    for (int nt = 0; nt < 4; ++nt) { ar[nt] = (f32x4){0.f,0.f,0.f,0.f}; ai[nt] = (f32x4){0.f,0.f,0.f,0.f}; }
#pragma unroll
    for (int nt = 0; nt < 4; ++nt) {
        int cc = m + 16 * nt;
#pragma unroll
        for (int ka = 0; ka < 4; ++ka) {
            int h0 = ka * 16 + q * 4;
            Bf.u2[0] = *(const uint2*)&zs[cc * 66 + h0];
            Bf.u2[1] = *(const uint2*)&zs[cc * 66 + h0 + 2];
            ar[nt] = __builtin_amdgcn_mfma_f32_16x16x32_bf16(Are[ka].v8, Bf.v8, ar[nt], 0, 0, 0);
            ai[nt] = __builtin_amdgcn_mfma_f32_16x16x32_bf16(Aim[ka].v8, Bf.v8, ai[nt], 0, 0, 0);
        }
    }
    // write X2 (b,h',w,t,c): b = s>>10, t = (s>>6)&15, w = s&63
    int b = s >> 10, t = (s >> 6) & 15, w = s & 63;
    size_t ob = (size_t)b * 4194304 + (size_t)w * 1024 + (size_t)t * 64;
#pragma unroll
    for (int nt = 0; nt < 4; ++nt) {
        int cc = m + 16 * nt;
#pragma unroll
        for (int reg = 0; reg < 4; ++reg) {
            int hp = r * 16 + q * 4 + reg;
            X2[ob + (size_t)hp * 65536 + cc] = bfpack(make_float2(ar[nt][reg], ai[nt][reg]));
        }
    }
}

// ---------------------------------------------------------------------------
// Pass 4: MFMA inverse DFT-64 along H. X3 (b,t,w,h,c) contiguous slab ->
// X4 (b,t,h,w,c). wg per (b,t,w). Scale 1/64 in table.
// ---------------------------------------------------------------------------
__global__ __launch_bounds__(256) void k_dft_h_inv(const unsigned* __restrict__ X3,
                                                   unsigned* __restrict__ X4,
                                                   const uint4* __restrict__ T) {
    __shared__ unsigned zs[64 * 66];
    int tid = threadIdx.x;
    int s = blockIdx.x;                // (b,t,w)
    const unsigned* src = X3 + (size_t)s * 4096;
    for (int i = tid; i < 4096; i += 256) {
        int h = i >> 6, c = i & 63;
        zs[c * 66 + h] = src[i];
    }
    __syncthreads();

    int r = tid >> 6, lane = tid & 63;
    int m = lane & 15, q = lane >> 4;
    union U48 { uint4 u4; uint2 u2[2]; unsigned u[4]; bf16x8 v8; };
    U48 Are[4], Aim[4], Bf;
#pragma unroll
    for (int ka = 0; ka < 4; ++ka) {
        Are[ka].u4 = T[((0 * 4 + r) * 4 + ka) * 64 + lane];
        Aim[ka].u4 = T[((1 * 4 + r) * 4 + ka) * 64 + lane];
    }
    f32x4 ar[4], ai[4];
#pragma unroll
    for (int nt = 0; nt < 4; ++nt) { ar[nt] = (f32x4){0.f,0.f,0.f,0.f}; ai[nt] = (f32x4){0.f,0.f,0.f,0.f}; }
#pragma unroll
    for (int nt = 0; nt < 4; ++nt) {
        int cc = m + 16 * nt;
#pragma unroll
        for (int ka = 0; ka < 4; ++ka) {
            int h0 = ka * 16 + q * 4;
            Bf.u2[0] = *(const uint2*)&zs[cc * 66 + h0];
            Bf.u2[1] = *(const uint2*)&zs[cc * 66 + h0 + 2];
            ar[nt] = __builtin_amdgcn_mfma_f32_16x16x32_bf16(Are[ka].v8, Bf.v8, ar[nt], 0, 0, 0);
            ai[nt] = __builtin_amdgcn_mfma_f32_16x16x32_bf16(Aim[ka].v8, Bf.v8, ai[nt], 0, 0, 0);
        }
    }
    // write X4 (b,t,h',w,c): bt = s>>6, w = s&63
    int bt = s >> 6, w = s & 63;
    size_t ob = (size_t)bt * 262144 + (size_t)w * 64;
#pragma unroll
    for (int nt = 0; nt < 4; ++nt) {
        int cc = m + 16 * nt;
#pragma unroll
        for (int reg = 0; reg < 4; ++reg) {
            int hp = r * 16 + q * 4 + reg;
            X4[ob + (size_t)hp * 4096 + cc] = bfpack(make_float2(ar[nt][reg], ai[nt][reg]));
        }
    }
}

// ---------------------------------------------------------------------------
// Pass 5: MFMA inverse DFT-64 along W, real out. X4 (b,t,h,w,c) contiguous
// slab -> out fp32 (same layout). wg per (b,t,h). Scale 1/64 in table.
// ---------------------------------------------------------------------------
__global__ __launch_bounds__(256) void k_dft_w_inv(const unsigned* __restrict__ X4,
                                                   float* __restrict__ out,
                                                   const uint4* __restrict__ T) {
    __shared__ unsigned zs[64 * 66];
    int tid = threadIdx.x;
    int s = blockIdx.x;                // (b,t,h)
    const unsigned* src = X4 + (size_t)s * 4096;
    for (int i = tid; i < 4096; i += 256) {
        int w = i >> 6, c = i & 63;
        zs[c * 66 + w] = src[i];
    }
    __syncthreads();

    int r = tid >> 6, lane = tid & 63;
    int m = lane & 15, q = lane >> 4;
    union U48 { uint4 u4; uint2 u2[2]; unsigned u[4]; bf16x8 v8; };
    U48 Are[4], Bf;
#pragma unroll
    for (int ka = 0; ka < 4; ++ka)
        Are[ka].u4 = T[(r * 4 + ka) * 64 + lane];
    f32x4 ar[4];
#pragma unroll
    for (int nt = 0; nt < 4; ++nt) ar[nt] = (f32x4){0.f,0.f,0.f,0.f};
#pragma unroll
    for (int nt = 0; nt < 4; ++nt) {
        int cc = m + 16 * nt;
#pragma unroll
        for (int ka = 0; ka < 4; ++ka) {
            int w0 = ka * 16 + q * 4;
            Bf.u2[0] = *(const uint2*)&zs[cc * 66 + w0];
            Bf.u2[1] = *(const uint2*)&zs[cc * 66 + w0 + 2];
            ar[nt] = __builtin_amdgcn_mfma_f32_16x16x32_bf16(Are[ka].v8, Bf.v8, ar[nt], 0, 0, 0);
        }
    }
    float* dst = out + (size_t)s * 4096;
#pragma unroll
    for (int nt = 0; nt < 4; ++nt) {
        int cc = m + 16 * nt;
#pragma unroll
        for (int reg = 0; reg < 4; ++reg) {
            int wp = r * 16 + q * 4 + reg;
            dst[wp * 64 + cc] = ar[nt][reg];
        }
    }
}

// ---------------------------------------------------------------------------
// k_mid: FFT-16 fwd along T + gates + MFMA delta-matmul + scan + FFT-16 inv.
// Reads X2 (b,h,w,t,c) -> site T-line is 4 KB CONTIGUOUS. Writes X3
// (b,t,w,h,c) (t-scattered 256B rows). 4 waves = 4 sites. Scale 1/16.
// ---------------------------------------------------------------------------
__global__ __launch_bounds__(256) void k_mid(
    const float* __restrict__ x, const unsigned* __restrict__ X2,
    unsigned* __restrict__ X3,
    const float* __restrict__ Ak, const float* __restrict__ Bk,
    const float* __restrict__ fb, const float* __restrict__ fs,
    const float* __restrict__ ib, const float* __restrict__ isc_,
    const uint4* __restrict__ pre, const float* __restrict__ db) {
    const float CT[16] = {1.f, 0.9238795f, 0.7071068f, 0.3826834f, 0.f, -0.3826834f,
                          -0.7071068f, -0.9238795f, -1.f, -0.9238795f, -0.7071068f,
                          -0.3826834f, 0.f, 0.3826834f, 0.7071068f, 0.9238795f};
    const float SN[16] = {0.f, 0.3826834f, 0.7071068f, 0.9238795f, 1.f, 0.9238795f,
                          0.7071068f, 0.3826834f, 0.f, -0.3826834f, -0.7071068f,
                          -0.9238795f, -1.f, -0.9238795f, -0.7071068f, -0.3826834f};
    __shared__ float Akl[1728], Bkl[1728];
    __shared__ __align__(16) float xs[4][16 * 68 + 4];

    int tid = threadIdx.x;
    int g = tid >> 6, lane = tid & 63;
    int c = lane;
    int site = blockIdx.x * 4 + g;
    int b = site >> 12, hw = site & 4095;
    int h = hw >> 6, w = hw & 63;
    size_t base = (size_t)b * SB_ + (size_t)hw * 64;

    for (int i = tid; i < 1728; i += 256) { Akl[i] = Ak[i]; Bkl[i] = Bk[i]; }

    float xv[16];
    float2 v[16];
    const unsigned* src2 = X2 + (size_t)site * 1024;
#pragma unroll
    for (int t = 0; t < 16; ++t) {
        xv[t] = x[base + (size_t)t * ST_ + c];
        v[t] = bfunpack(src2[t * 64 + c]);
    }
#pragma unroll
    for (int t = 0; t < 16; ++t) xs[g][t * 68 + c] = xv[t];
    __syncthreads();

    // MFMA delta matmul
    int m = lane & 15, q = lane >> 4;
    bf16x8 Afrag[2];
#pragma unroll
    for (int ka = 0; ka < 2; ++ka) {
        int d0 = ka * 32 + q * 8;
        const float* p = &xs[g][m * 68 + d0];
        float4 f0 = *(const float4*)p;
        float4 f1 = *(const float4*)(p + 4);
        union { bf16x8 v8; unsigned u[4]; } U;
        U.u[0] = bfpack(make_float2(f0.x, f0.y));
        U.u[1] = bfpack(make_float2(f0.z, f0.w));
        U.u[2] = bfpack(make_float2(f1.x, f1.y));
        U.u[3] = bfpack(make_float2(f1.z, f1.w));
        Afrag[ka] = U.v8;
    }
#pragma unroll
    for (int nt = 0; nt < 4; ++nt) {
        int ccol = m + 16 * nt;
        float dbn = db[ccol];
        f32x4 acc = {dbn, dbn, dbn, dbn};
#pragma unroll
        for (int ka = 0; ka < 2; ++ka) {
            union { bf16x8 v8; uint4 u4; } Ub;
            Ub.u4 = pre[(nt * 2 + ka) * 64 + lane];
            acc = __builtin_amdgcn_mfma_f32_16x16x32_bf16(Afrag[ka], Ub.v8, acc, 0, 0, 0);
        }
#pragma unroll
        for (int reg = 0; reg < 4; ++reg)
            xs[g][(q * 4 + reg) * 68 + ccol] = acc[reg];
    }

    // A_f/B_f generators from the 27 taps
    float sh, ch; sincosf(TWO_PI * (float)h / 64.0f, &sh, &ch);
    float sw, cw; sincosf(TWO_PI * (float)w / 64.0f, &sw, &cw);
    float2 eh[3] = { make_float2(ch, sh), make_float2(1.f, 0.f), make_float2(ch, -sh) };
    float2 ew[3] = { make_float2(cw, sw), make_float2(1.f, 0.f), make_float2(cw, -sw) };
    float2 GA[3], GB[3];
#pragma unroll
    for (int kt = 0; kt < 3; ++kt) { GA[kt] = make_float2(0.f, 0.f); GB[kt] = make_float2(0.f, 0.f); }
#pragma unroll
    for (int kh = 0; kh < 3; ++kh) {
#pragma unroll
        for (int kw = 0; kw < 3; ++kw) {
            float2 e = cmul(eh[kh], ew[kw]);
#pragma unroll
            for (int kt = 0; kt < 3; ++kt) {
                float ka = Akl[c * 27 + kt * 9 + kh * 3 + kw];
                float kb = Bkl[c * 27 + kt * 9 + kh * 3 + kw];
                GA[kt].x = fmaf(ka, e.x, GA[kt].x);
                GA[kt].y = fmaf(ka, e.y, GA[kt].y);
                GB[kt].x = fmaf(kb, e.x, GB[kt].x);
                GB[kt].y = fmaf(kb, e.y, GB[kt].y);
            }
        }
    }
    float fbc = fb[c], fsc = fs[c], ibc = ib[c], iscv = isc_[c];

    fft16<-1>(v);
    __syncthreads();

    float delta_raw[16];
#pragma unroll
    for (int t = 0; t < 16; ++t) delta_raw[t] = xs[g][t * 68 + c];

    float2 hv = make_float2(0.f, 0.f);
#pragma unroll
    for (int t = 0; t < 16; ++t) {
        float ct = CT[t], st = SN[t];
        float2 Af, Bf;
        Af.x = GA[1].x + ct * (GA[0].x + GA[2].x) - st * (GA[0].y - GA[2].y);
        Af.y = GA[1].y + ct * (GA[0].y + GA[2].y) + st * (GA[0].x - GA[2].x);
        Bf.x = GB[1].x + ct * (GB[0].x + GB[2].x) - st * (GB[0].y - GB[2].y);
        Bf.y = GB[1].y + ct * (GB[0].y + GB[2].y) + st * (GB[0].x - GB[2].x);

        float xc = xv[t];
        float fg  = __builtin_amdgcn_rcpf(1.f + __expf(-(fbc + fsc * xc)));
        float igv = __builtin_amdgcn_rcpf(1.f + __expf(-(ibc + iscv * xc)));
        float dot = delta_raw[t];
        float delta = (dot > 20.f) ? dot : __logf(1.f + __expf(dot));

        float sR = igv * delta;
        float2 bbv;
        bbv.x = sR * (Bf.x * v[t].x - Bf.y * v[t].y);
        bbv.y = sR * (Bf.x * v[t].y + Bf.y * v[t].x);
        float2 av = make_float2(fg * Af.x, fg * Af.y);
        float2 nh;
        nh.x = av.x * hv.x - av.y * hv.y + bbv.x;
        nh.y = av.x * hv.y + av.y * hv.x + bbv.y;
        hv = nh;
        v[t] = hv;
    }

    fft16<1>(v);

    // write X3 (b,t,w,h,c)
    size_t ob = (size_t)b * 4194304 + (size_t)w * 4096 + (size_t)h * 64 + c;
#pragma unroll
    for (int t = 0; t < 16; ++t) {
        float2 o = make_float2(v[t].x * 0.0625f, v[t].y * 0.0625f);
        X3[ob + (size_t)t * 262144] = bfpack(o);
    }
}

extern "C" void kernel_launch(void* const* d_in, const int* in_sizes, int n_in,
                              void* d_out, int out_size, void* d_ws, size_t ws_size,
                              hipStream_t stream) {
    const float* x   = (const float*)d_in[0];
    const float* Ak  = (const float*)d_in[1];
    const float* Bk  = (const float*)d_in[2];
    const float* fb  = (const float*)d_in[3];
    const float* fs  = (const float*)d_in[4];
    const float* ib  = (const float*)d_in[5];
    const float* is_ = (const float*)d_in[6];
    const float* dW  = (const float*)d_in[7];
    const float* db  = (const float*)d_in[8];
    float* out = (float*)d_out;
    unsigned* ws = (unsigned*)d_ws;
    unsigned* A = ws + BUF_A;
    unsigned* B = ws + BUF_B;

    k_setup<<<104, 256, 0, stream>>>(dW, ws);
    k_dft_w_fwd<<<Bb * Tt * Hh, 256, 0, stream>>>(x, A, (const uint4*)(ws + OFF_TWF));
    k_dft_h_fwd<<<Bb * Tt * Ww, 256, 0, stream>>>(A, B, (const uint4*)(ws + OFF_THF));
    k_mid<<<(Bb * Hh * Ww) / 4, 256, 0, stream>>>(x, B, A, Ak, Bk, fb, fs, ib, is_,
                                                  (const uint4*)(ws + OFF_PRE), db);
    k_dft_h_inv<<<Bb * Tt * Ww, 256, 0, stream>>>(A, B, (const uint4*)(ws + OFF_THI));
    k_dft_w_inv<<<Bb * Tt * Hh, 256, 0, stream>>>(B, out, (const uint4*)(ws + OFF_TWI));
}